// Round 1
// baseline (20713.387 us; speedup 1.0000x reference)
//
#include <hip/hip_runtime.h>
#include <hip/hip_bf16.h>
#include <math.h>

#define NP 16384
#define CI 512
#define CO 512
#define NE 262144
#define MS 8192
#define BN_EPS 1e-5f

// ---------------------------------------------------------------------------
// GEMM: H[n][o] = sum_k X[n][k]*W[o][k] + b[o]   (both row-major, K contiguous)
// 64x64 tile, BK=16, 256 threads, 4x4 micro-tile.
// ---------------------------------------------------------------------------
__global__ __launch_bounds__(256) void gemm_kernel(const float* __restrict__ X,
                                                   const float* __restrict__ W,
                                                   const float* __restrict__ bias,
                                                   float* __restrict__ H) {
  __shared__ float As[16][65];
  __shared__ float Bs[16][65];
  const int bm = blockIdx.x * 64;
  const int bn = blockIdx.y * 64;
  const int t  = threadIdx.x;
  const int tm = (t >> 4) << 2;   // 0..60
  const int tn = (t & 15) << 2;   // 0..60
  const int lr = t >> 2;          // 0..63 tile row to stage
  const int lc = (t & 3) << 2;    // 0,4,8,12 k offset

  float acc[4][4] = {};

  for (int k0 = 0; k0 < CI; k0 += 16) {
    float4 a = *(const float4*)(X + (size_t)(bm + lr) * CI + k0 + lc);
    float4 b = *(const float4*)(W + (size_t)(bn + lr) * CI + k0 + lc);
    As[lc + 0][lr] = a.x; As[lc + 1][lr] = a.y; As[lc + 2][lr] = a.z; As[lc + 3][lr] = a.w;
    Bs[lc + 0][lr] = b.x; Bs[lc + 1][lr] = b.y; Bs[lc + 2][lr] = b.z; Bs[lc + 3][lr] = b.w;
    __syncthreads();
#pragma unroll
    for (int k = 0; k < 16; ++k) {
      float av[4], bv[4];
#pragma unroll
      for (int i = 0; i < 4; ++i) av[i] = As[k][tm + i];
#pragma unroll
      for (int j = 0; j < 4; ++j) bv[j] = Bs[k][tn + j];
#pragma unroll
      for (int i = 0; i < 4; ++i)
#pragma unroll
        for (int j = 0; j < 4; ++j) acc[i][j] += av[i] * bv[j];
    }
    __syncthreads();
  }
#pragma unroll
  for (int i = 0; i < 4; ++i)
#pragma unroll
    for (int j = 0; j < 4; ++j)
      H[(size_t)(bm + tm + i) * CO + bn + tn + j] = acc[i][j] + bias[bn + tn + j];
}

// ---------------------------------------------------------------------------
// BN stats: deterministic two-stage (64 row-blocks x 512 cols partials)
// ---------------------------------------------------------------------------
__global__ __launch_bounds__(256) void bn_stats_kernel(const float* __restrict__ H,
                                                       float* __restrict__ psum,
                                                       float* __restrict__ psq) {
  const int col = blockIdx.x * 256 + threadIdx.x;  // blockIdx.x in {0,1}
  const int r0  = blockIdx.y * 256;                // blockIdx.y in [0,64)
  float s = 0.f, q = 0.f;
  for (int r = r0; r < r0 + 256; ++r) {
    float v = H[(size_t)r * CO + col];
    s += v;
    q += v * v;
  }
  psum[blockIdx.y * CO + col] = s;
  psq [blockIdx.y * CO + col] = q;
}

__global__ __launch_bounds__(512) void bn_final_kernel(const float* __restrict__ psum,
                                                       const float* __restrict__ psq,
                                                       const float* __restrict__ gamma,
                                                       const float* __restrict__ beta,
                                                       float* __restrict__ scale,
                                                       float* __restrict__ shift) {
  const int c = threadIdx.x;  // 512
  float s = 0.f, q = 0.f;
  for (int r = 0; r < 64; ++r) {  // fixed order -> deterministic
    s += psum[r * CO + c];
    q += psq [r * CO + c];
  }
  const float inv_n = 1.0f / (float)NP;
  float mu  = s * inv_n;
  float var = q * inv_n - mu * mu;
  float rs  = rsqrtf(var + BN_EPS);
  float a   = rs * gamma[c];
  scale[c] = a;
  shift[c] = beta[c] - mu * a;
}

__global__ __launch_bounds__(256) void bn_relu_kernel(float* __restrict__ H,
                                                      const float* __restrict__ scale,
                                                      const float* __restrict__ shift) {
  __shared__ float sc[CO], sh[CO];
  for (int i = threadIdx.x; i < CO; i += 256) { sc[i] = scale[i]; sh[i] = shift[i]; }
  __syncthreads();
  const int total4 = NP * CO / 4;
  const int stride = gridDim.x * blockDim.x;
  for (int idx = blockIdx.x * blockDim.x + threadIdx.x; idx < total4; idx += stride) {
    float4 v = ((float4*)H)[idx];
    int c = (idx << 2) & (CO - 1);
    v.x = fmaxf(fmaf(v.x, sc[c + 0], sh[c + 0]), 0.f);
    v.y = fmaxf(fmaf(v.y, sc[c + 1], sh[c + 1]), 0.f);
    v.z = fmaxf(fmaf(v.z, sc[c + 2], sh[c + 2]), 0.f);
    v.w = fmaxf(fmaf(v.w, sc[c + 3], sh[c + 3]), 0.f);
    ((float4*)H)[idx] = v;
  }
}

// ---------------------------------------------------------------------------
// FPS: single 1024-thread block; 16 points/thread in registers.
// Exact-rounding distance to match XLA: ((dx*dx + dy*dy) + dz*dz), no FMA.
// Argmax tie-break: lowest index (jnp.argmax first-occurrence).
// ---------------------------------------------------------------------------
__global__ __launch_bounds__(1024) void fps_kernel(const float* __restrict__ pos,
                                                   int* __restrict__ flags) {
  const int t = threadIdx.x;
  float px[16], py[16], pz[16], dmin[16];
#pragma unroll
  for (int k = 0; k < 16; ++k) {
    int i = k * 1024 + t;
    px[k] = pos[3 * i + 0];
    py[k] = pos[3 * i + 1];
    pz[k] = pos[3 * i + 2];
    dmin[k] = __builtin_huge_valf();
  }
  __shared__ float lx_s, ly_s, lz_s;
  __shared__ float rv[16];
  __shared__ int   ri[16];
  __shared__ int   widx_s;
  if (t == 0) {
    flags[0] = 1;
    lx_s = pos[0]; ly_s = pos[1]; lz_s = pos[2];
  }
  __syncthreads();

  for (int it = 1; it < MS; ++it) {
    const float lx = lx_s, ly = ly_s, lz = lz_s;
    float bv = -1.0f;
    int   bi = 0;
#pragma unroll
    for (int k = 0; k < 16; ++k) {
      float dx = __fsub_rn(px[k], lx);
      float dy = __fsub_rn(py[k], ly);
      float dz = __fsub_rn(pz[k], lz);
      float d  = __fadd_rn(__fadd_rn(__fmul_rn(dx, dx), __fmul_rn(dy, dy)),
                           __fmul_rn(dz, dz));
      float dm = fminf(dmin[k], d);
      dmin[k] = dm;
      if (dm > bv) { bv = dm; bi = k * 1024 + t; }  // k ascending => first-max kept
    }
    // wave (64-lane) argmax reduce, (max val, min idx)
#pragma unroll
    for (int off = 32; off; off >>= 1) {
      float ov = __shfl_xor(bv, off);
      int   oi = __shfl_xor(bi, off);
      if (ov > bv || (ov == bv && oi < bi)) { bv = ov; bi = oi; }
    }
    if ((t & 63) == 0) { rv[t >> 6] = bv; ri[t >> 6] = bi; }
    __syncthreads();
    if (t < 16) {
      bv = rv[t]; bi = ri[t];
#pragma unroll
      for (int off = 8; off; off >>= 1) {
        float ov = __shfl_xor(bv, off);
        int   oi = __shfl_xor(bi, off);
        if (ov > bv || (ov == bv && oi < bi)) { bv = ov; bi = oi; }
      }
      if (t == 0) { widx_s = bi; flags[bi] = 1; }
    }
    __syncthreads();
    const int w = widx_s;
    if ((w & 1023) == t) {  // owner broadcasts winner coords from registers
      int k = w >> 10;
      lx_s = px[k]; ly_s = py[k]; lz_s = pz[k];
    }
    __syncthreads();
  }
}

// ---------------------------------------------------------------------------
// Compact flags -> sorted selected indices (exclusive scan over 16384 flags)
// ---------------------------------------------------------------------------
__global__ __launch_bounds__(1024) void compact_kernel(const int* __restrict__ flags,
                                                       int* __restrict__ sel) {
  const int t = threadIdx.x;
  const int base = t * 16;
  int f[16];
  int cnt = 0;
#pragma unroll
  for (int j = 0; j < 16; ++j) { f[j] = flags[base + j]; cnt += f[j]; }
  const int lane = t & 63, wid = t >> 6;
  int incl = cnt;
#pragma unroll
  for (int off = 1; off < 64; off <<= 1) {
    int v = __shfl_up(incl, off);
    if (lane >= off) incl += v;
  }
  __shared__ int wtot[16];
  if (lane == 63) wtot[wid] = incl;
  __syncthreads();
  if (t < 16) {
    int v = wtot[t];
    int s = v;
#pragma unroll
    for (int off = 1; off < 16; off <<= 1) {
      int u = __shfl_up(s, off);
      if (t >= off) s += u;
    }
    wtot[t] = s - v;  // exclusive
  }
  __syncthreads();
  int off = wtot[wid] + incl - cnt;
#pragma unroll
  for (int j = 0; j < 16; ++j)
    if (f[j]) sel[off++] = base + j;
}

// ---------------------------------------------------------------------------
// Edge CSR by dst
// ---------------------------------------------------------------------------
__global__ __launch_bounds__(256) void edge_count_kernel(const int* __restrict__ edge,
                                                         int* __restrict__ count) {
  const int stride = gridDim.x * blockDim.x;
  for (int e = blockIdx.x * blockDim.x + threadIdx.x; e < NE; e += stride)
    atomicAdd(&count[edge[NE + e]], 1);
}

__global__ __launch_bounds__(1024) void scan_offsets_kernel(const int* __restrict__ count,
                                                            int* __restrict__ offs,
                                                            int* __restrict__ cursor) {
  const int t = threadIdx.x;
  const int base = t * 16;
  int c[16];
  int cnt = 0;
#pragma unroll
  for (int j = 0; j < 16; ++j) { c[j] = count[base + j]; cnt += c[j]; }
  const int lane = t & 63, wid = t >> 6;
  int incl = cnt;
#pragma unroll
  for (int off = 1; off < 64; off <<= 1) {
    int v = __shfl_up(incl, off);
    if (lane >= off) incl += v;
  }
  __shared__ int wtot[16];
  if (lane == 63) wtot[wid] = incl;
  __syncthreads();
  if (t < 16) {
    int v = wtot[t];
    int s = v;
#pragma unroll
    for (int off = 1; off < 16; off <<= 1) {
      int u = __shfl_up(s, off);
      if (t >= off) s += u;
    }
    wtot[t] = s - v;
  }
  __syncthreads();
  int off = wtot[wid] + incl - cnt;
#pragma unroll
  for (int j = 0; j < 16; ++j) {
    offs[base + j] = off;
    cursor[base + j] = off;
    off += c[j];
  }
  if (t == 1023) offs[NP] = off;
}

__global__ __launch_bounds__(256) void edge_scatter_kernel(const int* __restrict__ edge,
                                                           int* __restrict__ cursor,
                                                           int* __restrict__ esrc) {
  const int stride = gridDim.x * blockDim.x;
  for (int e = blockIdx.x * blockDim.x + threadIdx.x; e < NE; e += stride) {
    int p = atomicAdd(&cursor[edge[NE + e]], 1);
    esrc[p] = edge[e];
  }
}

// ---------------------------------------------------------------------------
// Pool: out[m] = max(H[sel[m]], max over incoming edges H[src])  (h>=0 post-ReLU)
// ---------------------------------------------------------------------------
__global__ __launch_bounds__(256) void pool_kernel(const float* __restrict__ H,
                                                   const int* __restrict__ sel,
                                                   const int* __restrict__ offs,
                                                   const int* __restrict__ esrc,
                                                   float* __restrict__ out) {
  const int m = blockIdx.x;
  const int i = sel[m];
  const int c = threadIdx.x;
  float v0 = H[(size_t)i * CO + c];
  float v1 = H[(size_t)i * CO + c + 256];
  const int s0 = offs[i], s1 = offs[i + 1];
  for (int k = s0; k < s1; ++k) {
    const int s = esrc[k];
    v0 = fmaxf(v0, H[(size_t)s * CO + c]);
    v1 = fmaxf(v1, H[(size_t)s * CO + c + 256]);
  }
  out[(size_t)m * CO + c] = v0;
  out[(size_t)m * CO + c + 256] = v1;
}

__global__ __launch_bounds__(256) void gather_pb_kernel(const float* __restrict__ pos,
                                                        const int* __restrict__ batch,
                                                        const int* __restrict__ sel,
                                                        float* __restrict__ out) {
  const int m = blockIdx.x * blockDim.x + threadIdx.x;
  if (m < MS) {
    const int i = sel[m];
    float* opos = out + (size_t)MS * CO;
    opos[3 * m + 0] = pos[3 * i + 0];
    opos[3 * m + 1] = pos[3 * i + 1];
    opos[3 * m + 2] = pos[3 * i + 2];
    ((int*)out)[(size_t)MS * CO + MS * 3 + m] = batch[i];
  }
}

// ---------------------------------------------------------------------------
extern "C" void kernel_launch(void* const* d_in, const int* in_sizes, int n_in,
                              void* d_out, int out_size, void* d_ws, size_t ws_size,
                              hipStream_t stream) {
  const float* x     = (const float*)d_in[0];
  const float* pos   = (const float*)d_in[1];
  const int*   batch = (const int*)  d_in[2];
  const int*   edge  = (const int*)  d_in[3];
  const float* W     = (const float*)d_in[4];
  const float* bias  = (const float*)d_in[5];
  const float* gamma = (const float*)d_in[6];
  const float* beta  = (const float*)d_in[7];
  float* out = (float*)d_out;

  // workspace bump allocator (256B aligned)
  char* ws = (char*)d_ws;
  size_t off = 0;
  auto alloc = [&](size_t bytes) -> void* {
    void* p = ws + off;
    off += (bytes + 255) & ~(size_t)255;
    return p;
  };
  float* H      = (float*)alloc((size_t)NP * CO * 4);  // 33.5 MB
  float* psum   = (float*)alloc(64 * CO * 4);
  float* psq    = (float*)alloc(64 * CO * 4);
  float* scale  = (float*)alloc(CO * 4);
  float* shift  = (float*)alloc(CO * 4);
  int*   flags  = (int*)  alloc(NP * 4);
  int*   sel    = (int*)  alloc(MS * 4);
  int*   count  = (int*)  alloc(NP * 4);
  int*   offs   = (int*)  alloc((NP + 1) * 4);
  int*   cursor = (int*)  alloc(NP * 4);
  int*   esrc   = (int*)  alloc(NE * 4);
  (void)ws_size;

  hipMemsetAsync(flags, 0, NP * 4, stream);
  hipMemsetAsync(count, 0, NP * 4, stream);

  // 1) Linear
  gemm_kernel<<<dim3(NP / 64, CO / 64), 256, 0, stream>>>(x, W, bias, H);
  // 2) BN stats + normalize + ReLU
  bn_stats_kernel<<<dim3(2, 64), 256, 0, stream>>>(H, psum, psq);
  bn_final_kernel<<<1, 512, 0, stream>>>(psum, psq, gamma, beta, scale, shift);
  bn_relu_kernel<<<2048, 256, 0, stream>>>(H, scale, shift);
  // 3) FPS (sequential; single workgroup)
  fps_kernel<<<1, 1024, 0, stream>>>(pos, flags);
  compact_kernel<<<1, 1024, 0, stream>>>(flags, sel);
  // 4) edge CSR by dst
  edge_count_kernel<<<512, 256, 0, stream>>>(edge, count);
  scan_offsets_kernel<<<1, 1024, 0, stream>>>(count, offs, cursor);
  edge_scatter_kernel<<<512, 256, 0, stream>>>(edge, cursor, esrc);
  // 5) pooled features for selected nodes + pos/batch gather
  pool_kernel<<<MS, 256, 0, stream>>>(H, sel, offs, esrc, out);
  gather_pb_kernel<<<MS / 256, 256, 0, stream>>>(pos, batch, sel, out);
}

// Round 2
// 10071.876 us; speedup vs baseline: 2.0566x; 2.0566x over previous
//
#include <hip/hip_runtime.h>
#include <hip/hip_bf16.h>
#include <math.h>

#define NP 16384
#define CI 512
#define CO 512
#define NE 262144
#define MS 8192
#define BN_EPS 1e-5f
#define NCELL 4096

// ---------------------------------------------------------------------------
// GEMM: H[n][o] = sum_k X[n][k]*W[o][k] + b[o]   (both row-major, K contiguous)
// ---------------------------------------------------------------------------
__global__ __launch_bounds__(256) void gemm_kernel(const float* __restrict__ X,
                                                   const float* __restrict__ W,
                                                   const float* __restrict__ bias,
                                                   float* __restrict__ H) {
  __shared__ float As[16][65];
  __shared__ float Bs[16][65];
  const int bm = blockIdx.x * 64;
  const int bn = blockIdx.y * 64;
  const int t  = threadIdx.x;
  const int tm = (t >> 4) << 2;
  const int tn = (t & 15) << 2;
  const int lr = t >> 2;
  const int lc = (t & 3) << 2;

  float acc[4][4] = {};

  for (int k0 = 0; k0 < CI; k0 += 16) {
    float4 a = *(const float4*)(X + (size_t)(bm + lr) * CI + k0 + lc);
    float4 b = *(const float4*)(W + (size_t)(bn + lr) * CI + k0 + lc);
    As[lc + 0][lr] = a.x; As[lc + 1][lr] = a.y; As[lc + 2][lr] = a.z; As[lc + 3][lr] = a.w;
    Bs[lc + 0][lr] = b.x; Bs[lc + 1][lr] = b.y; Bs[lc + 2][lr] = b.z; Bs[lc + 3][lr] = b.w;
    __syncthreads();
#pragma unroll
    for (int k = 0; k < 16; ++k) {
      float av[4], bv[4];
#pragma unroll
      for (int i = 0; i < 4; ++i) av[i] = As[k][tm + i];
#pragma unroll
      for (int j = 0; j < 4; ++j) bv[j] = Bs[k][tn + j];
#pragma unroll
      for (int i = 0; i < 4; ++i)
#pragma unroll
        for (int j = 0; j < 4; ++j) acc[i][j] += av[i] * bv[j];
    }
    __syncthreads();
  }
#pragma unroll
  for (int i = 0; i < 4; ++i)
#pragma unroll
    for (int j = 0; j < 4; ++j)
      H[(size_t)(bm + tm + i) * CO + bn + tn + j] = acc[i][j] + bias[bn + tn + j];
}

// ---------------------------------------------------------------------------
// BN
// ---------------------------------------------------------------------------
__global__ __launch_bounds__(256) void bn_stats_kernel(const float* __restrict__ H,
                                                       float* __restrict__ psum,
                                                       float* __restrict__ psq) {
  const int col = blockIdx.x * 256 + threadIdx.x;
  const int r0  = blockIdx.y * 256;
  float s = 0.f, q = 0.f;
  for (int r = r0; r < r0 + 256; ++r) {
    float v = H[(size_t)r * CO + col];
    s += v;
    q += v * v;
  }
  psum[blockIdx.y * CO + col] = s;
  psq [blockIdx.y * CO + col] = q;
}

__global__ __launch_bounds__(512) void bn_final_kernel(const float* __restrict__ psum,
                                                       const float* __restrict__ psq,
                                                       const float* __restrict__ gamma,
                                                       const float* __restrict__ beta,
                                                       float* __restrict__ scale,
                                                       float* __restrict__ shift) {
  const int c = threadIdx.x;
  float s = 0.f, q = 0.f;
  for (int r = 0; r < 64; ++r) {
    s += psum[r * CO + c];
    q += psq [r * CO + c];
  }
  const float inv_n = 1.0f / (float)NP;
  float mu  = s * inv_n;
  float var = q * inv_n - mu * mu;
  float rs  = rsqrtf(var + BN_EPS);
  float a   = rs * gamma[c];
  scale[c] = a;
  shift[c] = beta[c] - mu * a;
}

__global__ __launch_bounds__(256) void bn_relu_kernel(float* __restrict__ H,
                                                      const float* __restrict__ scale,
                                                      const float* __restrict__ shift) {
  __shared__ float sc[CO], sh[CO];
  for (int i = threadIdx.x; i < CO; i += 256) { sc[i] = scale[i]; sh[i] = shift[i]; }
  __syncthreads();
  const int total4 = NP * CO / 4;
  const int stride = gridDim.x * blockDim.x;
  for (int idx = blockIdx.x * blockDim.x + threadIdx.x; idx < total4; idx += stride) {
    float4 v = ((float4*)H)[idx];
    int c = (idx << 2) & (CO - 1);
    v.x = fmaxf(fmaf(v.x, sc[c + 0], sh[c + 0]), 0.f);
    v.y = fmaxf(fmaf(v.y, sc[c + 1], sh[c + 1]), 0.f);
    v.z = fmaxf(fmaf(v.z, sc[c + 2], sh[c + 2]), 0.f);
    v.w = fmaxf(fmaf(v.w, sc[c + 3], sh[c + 3]), 0.f);
    ((float4*)H)[idx] = v;
  }
}

// ---------------------------------------------------------------------------
// Spatial sort: Morton-cell counting sort (pruning locality for FPS).
// Within-cell order is nondeterministic (atomicAdd) -- harmless: per-point
// dmin values and the selected ORIGINAL indices are order-independent.
// ---------------------------------------------------------------------------
__device__ __forceinline__ unsigned p3(unsigned v) {
  v &= 0x3FFu;
  v = (v * 0x00010001u) & 0xFF0000FFu;
  v = (v * 0x00000101u) & 0x0F00F00Fu;
  v = (v * 0x00000011u) & 0xC30C30C3u;
  v = (v * 0x00000005u) & 0x49249249u;
  return v;
}

__global__ __launch_bounds__(256) void cell_kernel(const float* __restrict__ pos,
                                                   int* __restrict__ cid,
                                                   int* __restrict__ cnt) {
  int i = blockIdx.x * 256 + threadIdx.x;
  if (i < NP) {
    int cx = min(15, max(0, (int)(pos[3 * i + 0] * 16.f)));
    int cy = min(15, max(0, (int)(pos[3 * i + 1] * 16.f)));
    int cz = min(15, max(0, (int)(pos[3 * i + 2] * 16.f)));
    int c = (int)(p3(cx) | (p3(cy) << 1) | (p3(cz) << 2));
    cid[i] = c;
    atomicAdd(&cnt[c], 1);
  }
}

__global__ __launch_bounds__(1024) void cellscan_kernel(const int* __restrict__ cnt,
                                                        int* __restrict__ ccur) {
  const int t = threadIdx.x;
  const int base = t * 4;
  int c[4];
  int s = 0;
#pragma unroll
  for (int j = 0; j < 4; ++j) { c[j] = cnt[base + j]; s += c[j]; }
  const int lane = t & 63, wid = t >> 6;
  int incl = s;
#pragma unroll
  for (int off = 1; off < 64; off <<= 1) {
    int v = __shfl_up(incl, off);
    if (lane >= off) incl += v;
  }
  __shared__ int wtot[16];
  if (lane == 63) wtot[wid] = incl;
  __syncthreads();
  if (t < 16) {
    int v = wtot[t];
    int p = v;
#pragma unroll
    for (int off = 1; off < 16; off <<= 1) {
      int u = __shfl_up(p, off);
      if (t >= off) p += u;
    }
    wtot[t] = p - v;
  }
  __syncthreads();
  int off = wtot[wid] + incl - s;
#pragma unroll
  for (int j = 0; j < 4; ++j) { ccur[base + j] = off; off += c[j]; }
}

__global__ __launch_bounds__(256) void cellscatter_kernel(const float* __restrict__ pos,
                                                          const int* __restrict__ cid,
                                                          int* __restrict__ ccur,
                                                          float4* __restrict__ spos) {
  int i = blockIdx.x * 256 + threadIdx.x;
  if (i < NP) {
    int p = atomicAdd(&ccur[cid[i]], 1);
    spos[p] = make_float4(pos[3 * i + 0], pos[3 * i + 1], pos[3 * i + 2],
                          __int_as_float(i));
  }
}

// ---------------------------------------------------------------------------
// FPS with exact group pruning. 1024 threads x 16 consecutive sorted points.
// Skip rule: if dist(c,bbox)^2 * (1-1e-5) >= ub then no dmin in the group can
// change for this center, now or ever (distances static, dmin monotone down).
// Margin 1e-5 >> 3e-6 float error bound => never unsafely skips.
// Distance update keeps the exact XLA-matching rounding chain.
// One __syncthreads per iteration (double-buffered leader slots).
// ---------------------------------------------------------------------------
__global__ __launch_bounds__(1024) void fps_kernel(const float4* __restrict__ spos,
                                                   const float* __restrict__ pos,
                                                   int* __restrict__ flags) {
  const int t = threadIdx.x;
  float px[16], py[16], pz[16], dmin[16];
  float lox, loy, loz, hix, hiy, hiz;
#pragma unroll
  for (int k = 0; k < 16; ++k) {
    float4 p = spos[t * 16 + k];
    px[k] = p.x; py[k] = p.y; pz[k] = p.z;
    dmin[k] = __builtin_huge_valf();
    if (k == 0) { lox = hix = p.x; loy = hiy = p.y; loz = hiz = p.z; }
    else {
      lox = fminf(lox, p.x); hix = fmaxf(hix, p.x);
      loy = fminf(loy, p.y); hiy = fmaxf(hiy, p.y);
      loz = fminf(loz, p.z); hiz = fmaxf(hiz, p.z);
    }
  }
  __shared__ float lv[2][16];
  __shared__ int   li[2][16];
  float ub = __builtin_huge_valf();
  int aidx = t * 16;
  float cx = pos[0], cy = pos[1], cz = pos[2];
  if (t == 0) flags[0] = 1;

  for (int it = 1; it < MS; ++it) {
    // group prune test (conservative)
    float ddx = fmaxf(fmaxf(lox - cx, cx - hix), 0.f);
    float ddy = fmaxf(fmaxf(loy - cy, cy - hiy), 0.f);
    float ddz = fmaxf(fmaxf(loz - cz, cz - hiz), 0.f);
    float dlb2 = ddx * ddx + ddy * ddy + ddz * ddz;
    if (!(dlb2 * 0.99999f >= ub)) {
      float bv = -1.f; int bk = 0;
#pragma unroll
      for (int k = 0; k < 16; ++k) {
        float dx = __fsub_rn(px[k], cx);
        float dy = __fsub_rn(py[k], cy);
        float dz = __fsub_rn(pz[k], cz);
        float d  = __fadd_rn(__fadd_rn(__fmul_rn(dx, dx), __fmul_rn(dy, dy)),
                             __fmul_rn(dz, dz));
        float dm = fminf(dmin[k], d);
        dmin[k] = dm;
        if (dm > bv) { bv = dm; bk = t * 16 + k; }
      }
      ub = bv; aidx = bk;
    }
    // wave argmax: value-only fmax tree, then lane recovery via ballot
    float wv = ub;
#pragma unroll
    for (int off = 32; off; off >>= 1) wv = fmaxf(wv, __shfl_xor(wv, off));
    unsigned long long m = __ballot(ub == wv);
    int lane = __ffsll(m) - 1;
    int cand = __shfl(aidx, lane);
    const int b = it & 1;
    if ((t & 63) == 0) { lv[b][t >> 6] = wv; li[b][t >> 6] = cand; }
    __syncthreads();
    // every 16-lane group redundantly reduces the 16 leader slots
    float v  = lv[b][t & 15];
    int   i_ = li[b][t & 15];
#pragma unroll
    for (int off = 8; off; off >>= 1) {
      float ov = __shfl_xor(v, off);
      int   oi = __shfl_xor(i_, off);
      if (ov > v || (ov == v && oi < i_)) { v = ov; i_ = oi; }
    }
    float4 wc = spos[i_];   // single 16B load: x,y,z,orig-idx
    cx = wc.x; cy = wc.y; cz = wc.z;
    if (t == 0) flags[__float_as_int(wc.w)] = 1;
  }
}

// ---------------------------------------------------------------------------
// Compact flags -> sorted selected original indices
// ---------------------------------------------------------------------------
__global__ __launch_bounds__(1024) void compact_kernel(const int* __restrict__ flags,
                                                       int* __restrict__ sel) {
  const int t = threadIdx.x;
  const int base = t * 16;
  int f[16];
  int cnt = 0;
#pragma unroll
  for (int j = 0; j < 16; ++j) { f[j] = flags[base + j]; cnt += f[j]; }
  const int lane = t & 63, wid = t >> 6;
  int incl = cnt;
#pragma unroll
  for (int off = 1; off < 64; off <<= 1) {
    int v = __shfl_up(incl, off);
    if (lane >= off) incl += v;
  }
  __shared__ int wtot[16];
  if (lane == 63) wtot[wid] = incl;
  __syncthreads();
  if (t < 16) {
    int v = wtot[t];
    int s = v;
#pragma unroll
    for (int off = 1; off < 16; off <<= 1) {
      int u = __shfl_up(s, off);
      if (t >= off) s += u;
    }
    wtot[t] = s - v;
  }
  __syncthreads();
  int off = wtot[wid] + incl - cnt;
#pragma unroll
  for (int j = 0; j < 16; ++j)
    if (f[j]) sel[off++] = base + j;
}

// ---------------------------------------------------------------------------
// Edge CSR by dst
// ---------------------------------------------------------------------------
__global__ __launch_bounds__(256) void edge_count_kernel(const int* __restrict__ edge,
                                                         int* __restrict__ count) {
  const int stride = gridDim.x * blockDim.x;
  for (int e = blockIdx.x * blockDim.x + threadIdx.x; e < NE; e += stride)
    atomicAdd(&count[edge[NE + e]], 1);
}

__global__ __launch_bounds__(1024) void scan_offsets_kernel(const int* __restrict__ count,
                                                            int* __restrict__ offs,
                                                            int* __restrict__ cursor) {
  const int t = threadIdx.x;
  const int base = t * 16;
  int c[16];
  int cnt = 0;
#pragma unroll
  for (int j = 0; j < 16; ++j) { c[j] = count[base + j]; cnt += c[j]; }
  const int lane = t & 63, wid = t >> 6;
  int incl = cnt;
#pragma unroll
  for (int off = 1; off < 64; off <<= 1) {
    int v = __shfl_up(incl, off);
    if (lane >= off) incl += v;
  }
  __shared__ int wtot[16];
  if (lane == 63) wtot[wid] = incl;
  __syncthreads();
  if (t < 16) {
    int v = wtot[t];
    int s = v;
#pragma unroll
    for (int off = 1; off < 16; off <<= 1) {
      int u = __shfl_up(s, off);
      if (t >= off) s += u;
    }
    wtot[t] = s - v;
  }
  __syncthreads();
  int off = wtot[wid] + incl - cnt;
#pragma unroll
  for (int j = 0; j < 16; ++j) {
    offs[base + j] = off;
    cursor[base + j] = off;
    off += c[j];
  }
  if (t == 1023) offs[NP] = off;
}

__global__ __launch_bounds__(256) void edge_scatter_kernel(const int* __restrict__ edge,
                                                           int* __restrict__ cursor,
                                                           int* __restrict__ esrc) {
  const int stride = gridDim.x * blockDim.x;
  for (int e = blockIdx.x * blockDim.x + threadIdx.x; e < NE; e += stride) {
    int p = atomicAdd(&cursor[edge[NE + e]], 1);
    esrc[p] = edge[e];
  }
}

// ---------------------------------------------------------------------------
// Pool + gather
// ---------------------------------------------------------------------------
__global__ __launch_bounds__(256) void pool_kernel(const float* __restrict__ H,
                                                   const int* __restrict__ sel,
                                                   const int* __restrict__ offs,
                                                   const int* __restrict__ esrc,
                                                   float* __restrict__ out) {
  const int m = blockIdx.x;
  const int i = sel[m];
  const int c = threadIdx.x;
  float v0 = H[(size_t)i * CO + c];
  float v1 = H[(size_t)i * CO + c + 256];
  const int s0 = offs[i], s1 = offs[i + 1];
  for (int k = s0; k < s1; ++k) {
    const int s = esrc[k];
    v0 = fmaxf(v0, H[(size_t)s * CO + c]);
    v1 = fmaxf(v1, H[(size_t)s * CO + c + 256]);
  }
  out[(size_t)m * CO + c] = v0;
  out[(size_t)m * CO + c + 256] = v1;
}

__global__ __launch_bounds__(256) void gather_pb_kernel(const float* __restrict__ pos,
                                                        const int* __restrict__ batch,
                                                        const int* __restrict__ sel,
                                                        float* __restrict__ out) {
  const int m = blockIdx.x * blockDim.x + threadIdx.x;
  if (m < MS) {
    const int i = sel[m];
    float* opos = out + (size_t)MS * CO;
    opos[3 * m + 0] = pos[3 * i + 0];
    opos[3 * m + 1] = pos[3 * i + 1];
    opos[3 * m + 2] = pos[3 * i + 2];
    ((int*)out)[(size_t)MS * CO + MS * 3 + m] = batch[i];
  }
}

// ---------------------------------------------------------------------------
extern "C" void kernel_launch(void* const* d_in, const int* in_sizes, int n_in,
                              void* d_out, int out_size, void* d_ws, size_t ws_size,
                              hipStream_t stream) {
  const float* x     = (const float*)d_in[0];
  const float* pos   = (const float*)d_in[1];
  const int*   batch = (const int*)  d_in[2];
  const int*   edge  = (const int*)  d_in[3];
  const float* W     = (const float*)d_in[4];
  const float* bias  = (const float*)d_in[5];
  const float* gamma = (const float*)d_in[6];
  const float* beta  = (const float*)d_in[7];
  float* out = (float*)d_out;

  char* ws = (char*)d_ws;
  size_t off = 0;
  auto alloc = [&](size_t bytes) -> void* {
    void* p = ws + off;
    off += (bytes + 255) & ~(size_t)255;
    return p;
  };
  float*  H      = (float*)alloc((size_t)NP * CO * 4);
  float*  psum   = (float*)alloc(64 * CO * 4);
  float*  psq    = (float*)alloc(64 * CO * 4);
  float*  scale  = (float*)alloc(CO * 4);
  float*  shift  = (float*)alloc(CO * 4);
  int*    flags  = (int*)  alloc(NP * 4);
  int*    sel    = (int*)  alloc(MS * 4);
  int*    count  = (int*)  alloc(NP * 4);
  int*    offs   = (int*)  alloc((NP + 1) * 4);
  int*    cursor = (int*)  alloc(NP * 4);
  int*    esrc   = (int*)  alloc(NE * 4);
  int*    cid    = (int*)  alloc(NP * 4);
  int*    cnt    = (int*)  alloc(NCELL * 4);
  int*    ccur   = (int*)  alloc(NCELL * 4);
  float4* spos   = (float4*)alloc((size_t)NP * 16);
  (void)ws_size;

  hipMemsetAsync(flags, 0, NP * 4, stream);
  hipMemsetAsync(count, 0, NP * 4, stream);
  hipMemsetAsync(cnt,   0, NCELL * 4, stream);

  // spatial sort for FPS pruning
  cell_kernel<<<NP / 256, 256, 0, stream>>>(pos, cid, cnt);
  cellscan_kernel<<<1, 1024, 0, stream>>>(cnt, ccur);
  cellscatter_kernel<<<NP / 256, 256, 0, stream>>>(pos, cid, ccur, spos);
  // FPS
  fps_kernel<<<1, 1024, 0, stream>>>(spos, pos, flags);
  compact_kernel<<<1, 1024, 0, stream>>>(flags, sel);
  // Linear + BN + ReLU
  gemm_kernel<<<dim3(NP / 64, CO / 64), 256, 0, stream>>>(x, W, bias, H);
  bn_stats_kernel<<<dim3(2, 64), 256, 0, stream>>>(H, psum, psq);
  bn_final_kernel<<<1, 512, 0, stream>>>(psum, psq, gamma, beta, scale, shift);
  bn_relu_kernel<<<2048, 256, 0, stream>>>(H, scale, shift);
  // edge CSR by dst
  edge_count_kernel<<<512, 256, 0, stream>>>(edge, count);
  scan_offsets_kernel<<<1, 1024, 0, stream>>>(count, offs, cursor);
  edge_scatter_kernel<<<512, 256, 0, stream>>>(edge, cursor, esrc);
  // pooled features + pos/batch gather
  pool_kernel<<<MS, 256, 0, stream>>>(H, sel, offs, esrc, out);
  gather_pb_kernel<<<MS / 256, 256, 0, stream>>>(pos, batch, sel, out);
}